// Round 5
// baseline (1482.328 us; speedup 1.0000x reference)
//
#include <hip/hip_runtime.h>
#include <math.h>

#define H 4096
#define E 64
#define TOPK 8
#define EPS 2e-4f
#define KT 32            // k-tile
#define NT (H / KT)      // 128 tiles
#define RW 8             // rows per wave
#define RB 32            // rows per block (4 waves)

__global__ void init_cnt_kernel(unsigned int* cnt) {
    if (threadIdx.x == 0) cnt[0] = 0u;
}

// lane = expert. Wave w: rows [blk*32 + 8w, +8) over full K -> complete logits,
// no cross-wave reduce. W: LDS tile (xor-swizzle, 0-conflict per R3 profile) ->
// 32 VGPRs/tile reused over 8 rows. A: wave-uniform global_load_dwordx4 into
// NAMED even/odd register buffers, manual 2-way unroll (no pointer select -> no
// scratch; R4's 1 GB WRITE_SIZE came from exactly that).
__global__ __launch_bounds__(256, 2) void router_gemm_kernel(
    const float* __restrict__ A, const float* __restrict__ Wm,
    const float* __restrict__ bias, float* __restrict__ weights,
    float* __restrict__ indices, float* __restrict__ probs,
    unsigned int* __restrict__ cnt, unsigned int* __restrict__ list, int T)
{
    __shared__ float Wt[E * KT];   // 8 KB

    const int tid  = threadIdx.x;
    const int lane = tid & 63;
    const int wid  = tid >> 6;
    const long row0 = (long)blockIdx.x * RB + wid * RW;

    // W staging: thread t -> expert se = t>>2, chunks {c0, c0+4} of 8
    const int se = tid >> 2;
    const int c0 = tid & 3;

    float acc[RW];
#pragma unroll
    for (int r = 0; r < RW; ++r) acc[r] = 0.0f;

    // prefetch W tile 0
    float4 pw0 = *(const float4*)(Wm + (long)se * H + c0 * 4);
    float4 pw1 = *(const float4*)(Wm + (long)se * H + (c0 + 4) * 4);

    const float* aB = A + row0 * H;   // uniform within wave

    // A row buffers: even/odd, named, constant-indexed only
    float4 aEv[8], aOd[8];
#pragma unroll
    for (int j = 0; j < 8; ++j) aEv[j] = *(const float4*)(aB + j * 4);  // (t0,r0)

#pragma unroll 1
    for (int t = 0; t < NT; ++t) {
        const int k0 = t * KT;
        __syncthreads();   // previous tile's readers done
        *(float4*)&Wt[se * KT + (( c0      ^ (se & 7)) * 4)] = pw0;
        *(float4*)&Wt[se * KT + (((c0 + 4) ^ (se & 7)) * 4)] = pw1;
        __syncthreads();

        // my expert's fragment -> 32 VGPRs
        float4 wf[8];
#pragma unroll
        for (int g = 0; g < 8; ++g)
            wf[g] = *(const float4*)&Wt[lane * KT + ((g ^ (lane & 7)) * 4)];

        // prefetch next W tile (wraps harmlessly on last)
        const int kn = (t + 1 < NT) ? (k0 + KT) : 0;
        pw0 = *(const float4*)(Wm + (long)se * H + kn + c0 * 4);
        pw1 = *(const float4*)(Wm + (long)se * H + kn + (c0 + 4) * 4);

#pragma unroll
        for (int rp = 0; rp < RW / 2; ++rp) {
            {   // even row r = 2rp: prefetch row r+1 -> aOd, compute from aEv
                const int r = 2 * rp;
                const long noff = (long)(r + 1) * H + k0;
#pragma unroll
                for (int j = 0; j < 8; ++j)
                    aOd[j] = *(const float4*)(aB + noff + j * 4);
                float s = acc[r];
#pragma unroll
                for (int g = 0; g < 8; ++g) {
                    s = fmaf(aEv[g].x, wf[g].x, s);
                    s = fmaf(aEv[g].y, wf[g].y, s);
                    s = fmaf(aEv[g].z, wf[g].z, s);
                    s = fmaf(aEv[g].w, wf[g].w, s);
                }
                acc[r] = s;
            }
            {   // odd row r = 2rp+1: prefetch row r+1 (or next tile row 0) -> aEv
                const int r = 2 * rp + 1;
                const long noff = (r + 1 < RW) ? ((long)(r + 1) * H + k0) : (long)kn;
#pragma unroll
                for (int j = 0; j < 8; ++j)
                    aEv[j] = *(const float4*)(aB + noff + j * 4);
                float s = acc[r];
#pragma unroll
                for (int g = 0; g < 8; ++g) {
                    s = fmaf(aOd[g].x, wf[g].x, s);
                    s = fmaf(aOd[g].y, wf[g].y, s);
                    s = fmaf(aOd[g].z, wf[g].z, s);
                    s = fmaf(aOd[g].w, wf[g].w, s);
                }
                acc[r] = s;
            }
        }
    }

    // ---- epilogue: per-row butterfly top-9, gap test, outputs ----
    const float bv = bias[lane];
#pragma unroll 1
    for (int r = 0; r < RW; ++r) {
        const long row = row0 + r;
        const float logit = acc[r] + bv;

        probs[row * E + lane] = 1.f / (1.f + __expf(-logit));

        float cur = logit;
        float prev = 0.f, sum = 0.f, mingap = 3e38f;
        float myw = 0.f; int myi = 0;
#pragma unroll
        for (int it = 0; it < 9; ++it) {
            float bp = cur; int bi = lane;
#pragma unroll
            for (int off = 32; off >= 1; off >>= 1) {
                const float op = __shfl_xor(bp, off, 64);
                const int   oi = __shfl_xor(bi, off, 64);
                if (op > bp || (op == bp && oi < bi)) { bp = op; bi = oi; }
            }
            if (it > 0) mingap = fminf(mingap, prev - bp);
            prev = bp;
            if (it < TOPK) {
                const float p = 1.f / (1.f + __expf(-bp));
                sum += p;
                if (lane == it) { myw = p; myi = bi; }   // it is a constant per iter
            }
            if (lane == bi) cur = -3e38f;
        }
        if (lane < TOPK) {
            weights[row * TOPK + lane] = myw / sum;
            indices[row * TOPK + lane] = (float)myi;
        }
        if (lane == 0 && mingap < EPS) {
            const unsigned p = atomicAdd(cnt, 1u);
            if (p < (unsigned)T) list[p] = (unsigned)row;
        }
    }
}

// Exact f64 re-resolution: one wave per flagged row, coalesced loads, butterfly
// reduce + parallel top-8 (no dynamic local-array indexing).
__global__ __launch_bounds__(256) void fixup_kernel(
    const float* __restrict__ A, const float* __restrict__ Wm,
    const float* __restrict__ bias, float* __restrict__ weights,
    float* __restrict__ indices, const unsigned int* __restrict__ cnt,
    const unsigned int* __restrict__ list, int T)
{
    const int lane = threadIdx.x & 63;
    const int wid  = threadIdx.x >> 6;
    unsigned count = cnt[0];
    if (count > (unsigned)T) count = (unsigned)T;

    for (unsigned idx = blockIdx.x * 4 + wid; idx < count; idx += gridDim.x * 4) {
        const long row = (long)list[idx];
        double myv = 0.0;   // exact logit for expert == lane

#pragma unroll 1
        for (int e = 0; e < E; ++e) {
            double part = 0.0;
#pragma unroll 1
            for (int j = 0; j < 16; ++j) {
                const int k = j * 256 + lane * 4;
                const float4 a = *(const float4*)(A + row * H + k);
                const float4 w = *(const float4*)(Wm + (long)e * H + k);
                part = fma((double)a.x, (double)w.x, part);
                part = fma((double)a.y, (double)w.y, part);
                part = fma((double)a.z, (double)w.z, part);
                part = fma((double)a.w, (double)w.w, part);
            }
#pragma unroll
            for (int off = 32; off >= 1; off >>= 1)
                part += __shfl_xor(part, off, 64);
            if (lane == e) myv = part + (double)bias[e];
        }

        double cur = myv;
        float sum = 0.f, myw = 0.f; int myi = 0;
#pragma unroll
        for (int it = 0; it < TOPK; ++it) {
            double bp = cur; int bi = lane;
#pragma unroll
            for (int off = 32; off >= 1; off >>= 1) {
                const double op = __shfl_xor(bp, off, 64);
                const int    oi = __shfl_xor(bi, off, 64);
                if (op > bp || (op == bp && oi < bi)) { bp = op; bi = oi; }
            }
            const float p = 1.f / (1.f + __expf(-(float)bp));
            sum += p;
            if (lane == it) { myw = p; myi = bi; }
            if (lane == bi) cur = -1.0e300;
        }
        if (lane < TOPK) {
            weights[row * TOPK + lane] = myw / sum;
            indices[row * TOPK + lane] = (float)myi;
        }
    }
}

extern "C" void kernel_launch(void* const* d_in, const int* in_sizes, int n_in,
                              void* d_out, int out_size, void* d_ws, size_t ws_size,
                              hipStream_t stream) {
    const float* A    = (const float*)d_in[0];   // [T, H]
    const float* W    = (const float*)d_in[1];   // [E, H]
    const float* bias = (const float*)d_in[2];   // [E]
    const int T = in_sizes[0] / H;               // 16384

    float* out     = (float*)d_out;
    float* weights = out;                          // [T, 8]
    float* indices = out + (size_t)T * TOPK;       // [T, 8] (float-valued)
    float* probs   = out + (size_t)T * 2 * TOPK;   // [T, 64]

    unsigned int* cnt  = (unsigned int*)d_ws;      // [1]
    unsigned int* list = cnt + 8;                  // [T] flagged rows

    hipLaunchKernelGGL(init_cnt_kernel, dim3(1), dim3(64), 0, stream, cnt);
    hipLaunchKernelGGL(router_gemm_kernel, dim3(T / RB), dim3(256), 0, stream,
                       A, W, bias, weights, indices, probs, cnt, list, T);
    hipLaunchKernelGGL(fixup_kernel, dim3(256), dim3(256), 0, stream,
                       A, W, bias, weights, indices, cnt, list, T);
}

// Round 6
// 643.648 us; speedup vs baseline: 2.3030x; 2.3030x over previous
//
#include <hip/hip_runtime.h>
#include <math.h>

#define H 4096
#define E 64
#define TOPK 8
#define EPS 2e-4f
#define BM 64
#define SK 128
#define NS (H / SK)   // 32 stages

// prep: transpose W[e][k] -> Wt[k][e] in d_ws (1 MB), zero flag counter.
__global__ __launch_bounds__(256) void prep_kernel(
    const float* __restrict__ W, float* __restrict__ Wt, unsigned int* __restrict__ cnt)
{
    const int g = blockIdx.x * 256 + threadIdx.x;   // 0..65535
    if (g == 0) cnt[0] = 0u;
    const int k  = g >> 4;
    const int e4 = (g & 15) * 4;
    float4 v;
    v.x = W[(long)(e4 + 0) * H + k];
    v.y = W[(long)(e4 + 1) * H + k];
    v.z = W[(long)(e4 + 2) * H + k];
    v.w = W[(long)(e4 + 3) * H + k];
    *(float4*)&Wt[(long)k * E + e4] = v;   // coalesced write
}

// 512 threads = 8 waves. BM=64 rows x 64 experts per block, grid 256 (1/CU).
// Both operands k-major in LDS; 8x8 reg blocking: 16 ds_read_b128 per 256 fmac.
// Waves k-split the 32 chunks of each 128-k stage (4 chunks/wave, no intra-
// stage barriers); 3-round LDS tree merges partials; butterfly top-9 epilogue.
__global__ __launch_bounds__(512, 2) void router_gemm_kernel(
    const float* __restrict__ A, const float* __restrict__ Wt,
    const float* __restrict__ bias, float* __restrict__ weights,
    float* __restrict__ indices, float* __restrict__ probs,
    unsigned int* __restrict__ cnt, unsigned int* __restrict__ list, int T)
{
    __shared__ float smem[16384];          // 64 KB: A planes [0,8192), W [8192,16384)
    float* Als = smem;                     // [SK][64] r-chunks swizzled by (k&7)
    float* Wls = smem + SK * E;            // [SK][64] plain

    const int tid  = threadIdx.x;
    const int lane = tid & 63;
    const int wid  = tid >> 6;             // 0..7
    const int rg   = lane >> 3;            // row group: rows 8rg..8rg+7
    const int eg   = lane & 7;             // expert group: 8eg..8eg+7
    const long row0 = (long)blockIdx.x * BM;

    const int ar  = tid >> 3;              // A staging row 0..63
    const int ac0 = tid & 7;               // A staging chunk base
    const int wce = tid & 15;              // W staging e4
    const int wkq = tid >> 4;              // W staging k 0..31

    float acc[8][8];
#pragma unroll
    for (int i = 0; i < 8; ++i)
#pragma unroll
        for (int j = 0; j < 8; ++j) acc[i][j] = 0.f;

    const float* aP = A + (row0 + ar) * (long)H;
    float4 pa[4], pw[4];
#pragma unroll
    for (int j = 0; j < 4; ++j) pa[j] = *(const float4*)(aP + (ac0 + 8 * j) * 4);
#pragma unroll
    for (int j = 0; j < 4; ++j) pw[j] = *(const float4*)(Wt + (long)(wkq + 32 * j) * E + 4 * wce);

#pragma unroll 1
    for (int s = 0; s < NS; ++s) {
        __syncthreads();                   // previous stage's readers done
        // A -> k-major planes, b32 scatter, swizzle rc^(k&7) (4-way, ~9cyc)
#pragma unroll
        for (int j = 0; j < 4; ++j) {
            const int kA = 4 * (ac0 + 8 * j);
            Als[(kA + 0) * E + 4 * ((ar >> 2) ^ ((kA + 0) & 7)) + (ar & 3)] = pa[j].x;
            Als[(kA + 1) * E + 4 * ((ar >> 2) ^ ((kA + 1) & 7)) + (ar & 3)] = pa[j].y;
            Als[(kA + 2) * E + 4 * ((ar >> 2) ^ ((kA + 2) & 7)) + (ar & 3)] = pa[j].z;
            Als[(kA + 3) * E + 4 * ((ar >> 2) ^ ((kA + 3) & 7)) + (ar & 3)] = pa[j].w;
        }
#pragma unroll
        for (int j = 0; j < 4; ++j)
            *(float4*)&Wls[(wkq + 32 * j) * E + 4 * wce] = pw[j];
        __syncthreads();

        if (s + 1 < NS) {                  // prefetch next stage (in flight over compute)
            const int kb = (s + 1) * SK;
#pragma unroll
            for (int j = 0; j < 4; ++j) pa[j] = *(const float4*)(aP + kb + (ac0 + 8 * j) * 4);
#pragma unroll
            for (int j = 0; j < 4; ++j) pw[j] = *(const float4*)(Wt + (long)(kb + wkq + 32 * j) * E + 4 * wce);
        }

#pragma unroll 1
        for (int cc = 0; cc < 4; ++cc) {
            const int c = wid + 8 * cc;    // my chunk (k-split across waves)
            float4 af[4][2], wf[4][2];
#pragma unroll
            for (int k4 = 0; k4 < 4; ++k4) {
                const int k  = 4 * c + k4;
                const int sw = k & 7;
                af[k4][0] = *(const float4*)&Als[k * E + 4 * ((2 * rg + 0) ^ sw)];
                af[k4][1] = *(const float4*)&Als[k * E + 4 * ((2 * rg + 1) ^ sw)];
                wf[k4][0] = *(const float4*)&Wls[k * E + 8 * eg];
                wf[k4][1] = *(const float4*)&Wls[k * E + 8 * eg + 4];
            }
#pragma unroll
            for (int k4 = 0; k4 < 4; ++k4) {
#pragma unroll
                for (int i = 0; i < 8; ++i) {
                    const float a = ((const float*)&af[k4][i >> 2])[i & 3];
#pragma unroll
                    for (int j = 0; j < 8; ++j)
                        acc[i][j] = fmaf(a, ((const float*)&wf[k4][j >> 2])[j & 3], acc[i][j]);
                }
            }
        }
    }

    // ---- cross-wave k-reduce: 3 tree rounds through smem ----
#define SLOT_WRITE(S)                                                                        \
    {   const int s_ = (S);                                                                  \
        _Pragma("unroll")                                                                    \
        for (int i = 0; i < 8; ++i) {                                                        \
            *(float4*)&smem[s_ * 64 + 4 * ((2 * i + 0) ^ (s_ & 7))] =                        \
                make_float4(acc[i][0], acc[i][1], acc[i][2], acc[i][3]);                     \
            *(float4*)&smem[s_ * 64 + 4 * ((2 * i + 1) ^ (s_ & 7))] =                        \
                make_float4(acc[i][4], acc[i][5], acc[i][6], acc[i][7]);                     \
        } }
#define SLOT_ADD(S)                                                                          \
    {   const int s_ = (S);                                                                  \
        _Pragma("unroll")                                                                    \
        for (int i = 0; i < 8; ++i) {                                                        \
            const float4 u = *(const float4*)&smem[s_ * 64 + 4 * ((2 * i + 0) ^ (s_ & 7))];  \
            const float4 v = *(const float4*)&smem[s_ * 64 + 4 * ((2 * i + 1) ^ (s_ & 7))];  \
            acc[i][0] += u.x; acc[i][1] += u.y; acc[i][2] += u.z; acc[i][3] += u.w;          \
            acc[i][4] += v.x; acc[i][5] += v.y; acc[i][6] += v.z; acc[i][7] += v.w;          \
        } }

    __syncthreads();
    if (wid >= 4) SLOT_WRITE((wid - 4) * 64 + lane);
    __syncthreads();
    if (wid < 4) SLOT_ADD(wid * 64 + lane);
    __syncthreads();
    if (wid == 2 || wid == 3) SLOT_WRITE((wid - 2) * 64 + lane);
    __syncthreads();
    if (wid < 2) SLOT_ADD(wid * 64 + lane);
    __syncthreads();
    if (wid == 1) SLOT_WRITE(lane);
    __syncthreads();
    if (wid == 0) {
        SLOT_ADD(lane);
        // publish final logits: Llds at smem+8192, stride 68 (2-way-free reads)
#pragma unroll
        for (int i = 0; i < 8; ++i) {
            *(float4*)&smem[8192 + (8 * rg + i) * 68 + 8 * eg] =
                make_float4(acc[i][0], acc[i][1], acc[i][2], acc[i][3]);
            *(float4*)&smem[8192 + (8 * rg + i) * 68 + 8 * eg + 4] =
                make_float4(acc[i][4], acc[i][5], acc[i][6], acc[i][7]);
        }
    }
    __syncthreads();

    // ---- epilogue: wave w rows 8w..8w+7, lane=expert butterfly top-9 ----
    const float bv = bias[lane];
#pragma unroll 1
    for (int rr = 0; rr < 8; ++rr) {
        const int  rl  = 8 * wid + rr;
        const long row = row0 + rl;
        const float logit = smem[8192 + rl * 68 + lane] + bv;

        probs[row * E + lane] = 1.f / (1.f + __expf(-logit));

        float cur = logit;
        float prev = 0.f, sum = 0.f, mingap = 3e38f;
        float myw = 0.f; int myi = 0;
#pragma unroll
        for (int it = 0; it < 9; ++it) {
            float bp = cur; int bi = lane;
#pragma unroll
            for (int off = 32; off >= 1; off >>= 1) {
                const float op = __shfl_xor(bp, off, 64);
                const int   oi = __shfl_xor(bi, off, 64);
                if (op > bp || (op == bp && oi < bi)) { bp = op; bi = oi; }
            }
            if (it > 0) mingap = fminf(mingap, prev - bp);
            prev = bp;
            if (it < TOPK) {
                const float p = 1.f / (1.f + __expf(-bp));
                sum += p;
                if (lane == it) { myw = p; myi = bi; }
            }
            if (lane == bi) cur = -3e38f;
        }
        if (lane < TOPK) {
            weights[row * TOPK + lane] = myw / sum;
            indices[row * TOPK + lane] = (float)myi;
        }
        if (lane == 0 && mingap < EPS) {
            const unsigned p = atomicAdd(cnt, 1u);
            if (p < (unsigned)T) list[p] = (unsigned)row;
        }
    }
}

// Exact f64 re-resolution: one wave per flagged row; 4 independent FMA chains.
__global__ __launch_bounds__(256) void fixup_kernel(
    const float* __restrict__ A, const float* __restrict__ Wm,
    const float* __restrict__ bias, float* __restrict__ weights,
    float* __restrict__ indices, const unsigned int* __restrict__ cnt,
    const unsigned int* __restrict__ list, int T)
{
    const int lane = threadIdx.x & 63;
    const int wid  = threadIdx.x >> 6;
    unsigned count = cnt[0];
    if (count > (unsigned)T) count = (unsigned)T;

    for (unsigned idx = blockIdx.x * 4 + wid; idx < count; idx += gridDim.x * 4) {
        const long row = (long)list[idx];
        double myv = 0.0;

#pragma unroll 1
        for (int e = 0; e < E; ++e) {
            double p0 = 0, p1 = 0, p2 = 0, p3 = 0;
#pragma unroll 1
            for (int jj = 0; jj < 4; ++jj) {
                const int kb = jj * 1024 + lane * 4;
                const float4 a0 = *(const float4*)(A + row * H + kb);
                const float4 w0 = *(const float4*)(Wm + (long)e * H + kb);
                const float4 a1 = *(const float4*)(A + row * H + kb + 256);
                const float4 w1 = *(const float4*)(Wm + (long)e * H + kb + 256);
                const float4 a2 = *(const float4*)(A + row * H + kb + 512);
                const float4 w2 = *(const float4*)(Wm + (long)e * H + kb + 512);
                const float4 a3 = *(const float4*)(A + row * H + kb + 768);
                const float4 w3 = *(const float4*)(Wm + (long)e * H + kb + 768);
                p0 = fma((double)a0.x, (double)w0.x, p0); p0 = fma((double)a0.y, (double)w0.y, p0);
                p0 = fma((double)a0.z, (double)w0.z, p0); p0 = fma((double)a0.w, (double)w0.w, p0);
                p1 = fma((double)a1.x, (double)w1.x, p1); p1 = fma((double)a1.y, (double)w1.y, p1);
                p1 = fma((double)a1.z, (double)w1.z, p1); p1 = fma((double)a1.w, (double)w1.w, p1);
                p2 = fma((double)a2.x, (double)w2.x, p2); p2 = fma((double)a2.y, (double)w2.y, p2);
                p2 = fma((double)a2.z, (double)w2.z, p2); p2 = fma((double)a2.w, (double)w2.w, p2);
                p3 = fma((double)a3.x, (double)w3.x, p3); p3 = fma((double)a3.y, (double)w3.y, p3);
                p3 = fma((double)a3.z, (double)w3.z, p3); p3 = fma((double)a3.w, (double)w3.w, p3);
            }
            double part = (p0 + p1) + (p2 + p3);
#pragma unroll
            for (int off = 32; off >= 1; off >>= 1)
                part += __shfl_xor(part, off, 64);
            if (lane == e) myv = part + (double)bias[e];
        }

        double cur = myv;
        float sum = 0.f, myw = 0.f; int myi = 0;
#pragma unroll
        for (int it = 0; it < TOPK; ++it) {
            double bp = cur; int bi = lane;
#pragma unroll
            for (int off = 32; off >= 1; off >>= 1) {
                const double op = __shfl_xor(bp, off, 64);
                const int    oi = __shfl_xor(bi, off, 64);
                if (op > bp || (op == bp && oi < bi)) { bp = op; bi = oi; }
            }
            const float p = 1.f / (1.f + __expf(-(float)bp));
            sum += p;
            if (lane == it) { myw = p; myi = bi; }
            if (lane == bi) cur = -1.0e300;
        }
        if (lane < TOPK) {
            weights[row * TOPK + lane] = myw / sum;
            indices[row * TOPK + lane] = (float)myi;
        }
    }
}

extern "C" void kernel_launch(void* const* d_in, const int* in_sizes, int n_in,
                              void* d_out, int out_size, void* d_ws, size_t ws_size,
                              hipStream_t stream) {
    const float* A    = (const float*)d_in[0];   // [T, H]
    const float* W    = (const float*)d_in[1];   // [E, H]
    const float* bias = (const float*)d_in[2];   // [E]
    const int T = in_sizes[0] / H;               // 16384

    float* out     = (float*)d_out;
    float* weights = out;                          // [T, 8]
    float* indices = out + (size_t)T * TOPK;       // [T, 8] (float-valued)
    float* probs   = out + (size_t)T * 2 * TOPK;   // [T, 64]

    unsigned int* cnt  = (unsigned int*)d_ws;                      // [1]
    unsigned int* list = cnt + 8;                                  // [T]
    float*        Wt   = (float*)((char*)d_ws + 131072);           // [4096][64], 1 MB

    hipLaunchKernelGGL(prep_kernel, dim3(256), dim3(256), 0, stream, W, Wt, cnt);
    hipLaunchKernelGGL(router_gemm_kernel, dim3(T / BM), dim3(512), 0, stream,
                       A, Wt, bias, weights, indices, probs, cnt, list, T);
    hipLaunchKernelGGL(fixup_kernel, dim3(256), dim3(256), 0, stream,
                       A, W, bias, weights, indices, cnt, list, T);
}